// Round 1
// baseline (41.779 us; speedup 1.0000x reference)
//
#include <hip/hip_runtime.h>
#include <math.h>

#define EPSN 1e-12f

// ---------------------------------------------------------------------------
// Kernel 1: rnorm[e,m] = 1 / max(||A[e,:,m]||_2, eps)   (E*N = 512 values)
// ---------------------------------------------------------------------------
__global__ void colnorm_kernel(const float* __restrict__ A, float* __restrict__ rnorm) {
    int e = blockIdx.x;          // 0..3
    int m = threadIdx.x;         // 0..127
    const float* Ae = A + e * 128 * 128;
    float s = 0.0f;
    #pragma unroll 8
    for (int n = 0; n < 128; ++n) {
        float v = Ae[n * 128 + m];     // coalesced across m
        s += v * v;
    }
    rnorm[e * 128 + m] = 1.0f / fmaxf(sqrtf(s), EPSN);
}

// ---------------------------------------------------------------------------
// Kernel 2: per (b,c) block.
//   XW[e,n,o] = sum_f x[b,c,n,f] * W[e,f,o]          (LDS, 4x128x4)
//   out[b, e*16+c, m, o] = relu( rnorm[e,m] * sum_n A[e,n,m] * XW[e,n,o] )
// ---------------------------------------------------------------------------
__global__ __launch_bounds__(256)
void gcn_kernel(const float* __restrict__ x, const float* __restrict__ A,
                const float* __restrict__ W, const float* __restrict__ rnorm,
                float* __restrict__ out) {
    __shared__ float xl[128][17];      // x tile, padded (+1) against bank conflicts
    __shared__ float xw[4][128][4];    // XW tile (float4-aligned rows)

    const int t  = threadIdx.x;        // 0..255
    const int bc = blockIdx.x;         // b*16 + c
    const int b  = bc >> 4;
    const int c  = bc & 15;

    // ---- stage x[b,c,:,:] (128x16 f32 = 8 KB) via float4 loads ----
    const float* xp = x + (size_t)bc * 2048;
    #pragma unroll
    for (int i = t; i < 512; i += 256) {
        float4 v = ((const float4*)xp)[i];
        int n = i >> 2;
        int f = (i & 3) * 4;
        xl[n][f + 0] = v.x;
        xl[n][f + 1] = v.y;
        xl[n][f + 2] = v.z;
        xl[n][f + 3] = v.w;
    }
    __syncthreads();

    // ---- XW[e,n,:] : 512 (e,n) pairs, 2 per thread ----
    #pragma unroll
    for (int iter = 0; iter < 2; ++iter) {
        int idx = iter * 256 + t;      // 0..511
        int e = idx >> 7;              // 0..3
        int n = idx & 127;
        const float* We = W + e * 64;  // [16][4]
        float a0 = 0.f, a1 = 0.f, a2 = 0.f, a3 = 0.f;
        #pragma unroll
        for (int f = 0; f < 16; ++f) {
            float xv = xl[n][f];
            a0 += xv * We[f * 4 + 0];
            a1 += xv * We[f * 4 + 1];
            a2 += xv * We[f * 4 + 2];
            a3 += xv * We[f * 4 + 3];
        }
        xw[e][n][0] = a0; xw[e][n][1] = a1; xw[e][n][2] = a2; xw[e][n][3] = a3;
    }
    __syncthreads();

    // ---- main reduction over n: each thread owns (e,m), 4 outputs ----
    #pragma unroll
    for (int iter = 0; iter < 2; ++iter) {
        int idx = iter * 256 + t;      // 0..511
        int e = idx >> 7;              // wave-uniform (64 | 128 granularity)
        int m = idx & 127;             // consecutive across lanes -> coalesced A reads
        const float* Ae = A + e * 16384 + m;
        float a0 = 0.f, a1 = 0.f, a2 = 0.f, a3 = 0.f;
        #pragma unroll 8
        for (int n = 0; n < 128; ++n) {
            float av = Ae[n * 128];                     // global, coalesced, L2-hot
            float4 w4 = *(const float4*)&xw[e][n][0];   // ds_read_b128, wave-broadcast
            a0 += av * w4.x;
            a1 += av * w4.y;
            a2 += av * w4.z;
            a3 += av * w4.w;
        }
        float r = rnorm[e * 128 + m];
        float4 o4;
        o4.x = fmaxf(a0 * r, 0.0f);
        o4.y = fmaxf(a1 * r, 0.0f);
        o4.z = fmaxf(a2 * r, 0.0f);
        o4.w = fmaxf(a3 * r, 0.0f);
        // out[b, e*16 + c, m, 0..3]
        size_t oi = ((size_t)(b * 64 + e * 16 + c) * 128 + m);
        ((float4*)out)[oi] = o4;
    }
}

extern "C" void kernel_launch(void* const* d_in, const int* in_sizes, int n_in,
                              void* d_out, int out_size, void* d_ws, size_t ws_size,
                              hipStream_t stream) {
    const float* x = (const float*)d_in[0];   // [128,16,128,16]
    const float* A = (const float*)d_in[1];   // [4,128,128]
    const float* W = (const float*)d_in[2];   // [4,16,4]
    float* out = (float*)d_out;               // [128,64,128,4]
    float* rnorm = (float*)d_ws;              // 512 floats

    colnorm_kernel<<<4, 128, 0, stream>>>(A, rnorm);
    gcn_kernel<<<128 * 16, 256, 0, stream>>>(x, A, W, rnorm, out);
}

// Round 2
// 23.104 us; speedup vs baseline: 1.8083x; 1.8083x over previous
//
#include <hip/hip_runtime.h>
#include <math.h>

#define EPSN 1e-12f

typedef __attribute__((ext_vector_type(8))) __bf16 bf16x8;
typedef __attribute__((ext_vector_type(8))) short short8;
typedef __attribute__((ext_vector_type(4))) float floatx4;

static __device__ __forceinline__ unsigned short f2bf(float f) {
    return __builtin_bit_cast(unsigned short, (__bf16)f);
}

// ---------------------------------------------------------------------------
// Prep: At[e][m][n] = bf16( A[e][n][m] / max(||A[e][:][m]||_2, eps) )
// grid = 16 blocks (e in 0..3, m-chunk of 32), 256 threads
// ---------------------------------------------------------------------------
__global__ __launch_bounds__(256)
void prep_kernel(const float* __restrict__ A, unsigned short* __restrict__ At) {
    __shared__ float Asub[128][33];   // [n][m_local], padded
    __shared__ float red[8][32];
    __shared__ float rnv[32];
    const int t  = threadIdx.x;
    const int e  = blockIdx.x >> 2;
    const int m0 = (blockIdx.x & 3) * 32;
    const float* Ae = A + e * 16384 + m0;

    // load 128n x 32m slice (coalesced in m)
    #pragma unroll
    for (int i = 0; i < 16; ++i) {
        int idx = t + i * 256;            // 0..4095
        int n = idx >> 5, ml = idx & 31;
        Asub[n][ml] = Ae[n * 128 + ml];
    }
    __syncthreads();

    // column norms: 8 partial sums of 16 rows each
    {
        int ml = t & 31, g = t >> 5;
        float s = 0.f;
        #pragma unroll
        for (int j = 0; j < 16; ++j) {
            float v = Asub[g * 16 + j][ml];
            s += v * v;
        }
        red[g][ml] = s;
    }
    __syncthreads();
    if (t < 32) {
        float s = 0.f;
        #pragma unroll
        for (int g = 0; g < 8; ++g) s += red[g][t];
        rnv[t] = 1.0f / fmaxf(sqrtf(s), EPSN);
    }
    __syncthreads();

    // transposed, normalized, bf16 write: thread -> (m_local = t>>3, 16 n's)
    {
        int ml = t >> 3;
        int n0 = (t & 7) * 16;
        float r = rnv[ml];
        unsigned short hs[16];
        #pragma unroll
        for (int j = 0; j < 16; ++j)
            hs[j] = f2bf(Asub[n0 + j][ml] * r);
        uint4* dst = (uint4*)(At + ((size_t)(e * 128 + m0 + ml) * 128 + n0));
        dst[0] = *(const uint4*)&hs[0];
        dst[1] = *(const uint4*)&hs[8];
    }
}

// ---------------------------------------------------------------------------
// Main: per block 4 bc's. Phase 1: XW = x@W -> LDS bf16 [e][r=(bc,o)][n],
// XOR-swizzled. Phase 2: wave e: out[(bc,o), m] = relu( XW_e . At_e^T ) via
// mfma_f32_16x16x32_bf16, coalesced float4 stores.
// ---------------------------------------------------------------------------
__global__ __launch_bounds__(256)
void gcn_mfma_kernel(const float* __restrict__ x, const float* __restrict__ W,
                     const unsigned short* __restrict__ At,
                     float* __restrict__ out) {
    __shared__ __align__(16) unsigned short xw[8192];  // 4e x 16r x 128n bf16, swizzled

    const int t   = threadIdx.x;
    const int bc0 = blockIdx.x * 4;

    // ---- phase 1: each thread handles 2 (bc_local, n) pairs ----
    float4 xf[2][4];
    int bcl_[2], n_[2];
    #pragma unroll
    for (int p = 0; p < 2; ++p) {
        int pair = t + p * 256;           // 0..511
        int bcl = pair >> 7, n = pair & 127;
        bcl_[p] = bcl; n_[p] = n;
        const float4* xp = (const float4*)(x + ((size_t)(bc0 + bcl) * 128 + n) * 16);
        xf[p][0] = xp[0]; xf[p][1] = xp[1]; xf[p][2] = xp[2]; xf[p][3] = xp[3];
    }
    #pragma unroll 1
    for (int e = 0; e < 4; ++e) {
        float4 We[16];                    // wave-uniform -> scalar loads
        const float4* wp = (const float4*)(W + e * 64);
        #pragma unroll
        for (int f = 0; f < 16; ++f) We[f] = wp[f];
        #pragma unroll
        for (int p = 0; p < 2; ++p) {
            float a0 = 0.f, a1 = 0.f, a2 = 0.f, a3 = 0.f;
            #pragma unroll
            for (int f = 0; f < 16; ++f) {
                float xv = ((const float*)&xf[p][f >> 2])[f & 3];
                a0 += xv * We[f].x; a1 += xv * We[f].y;
                a2 += xv * We[f].z; a3 += xv * We[f].w;
            }
            float av[4] = {a0, a1, a2, a3};
            int n = n_[p];
            #pragma unroll
            for (int o = 0; o < 4; ++o) {
                int r = bcl_[p] * 4 + o;
                int byteoff = (((e * 16 + r) << 8) + (n << 1)) ^ ((r & 7) << 4);
                *(unsigned short*)((char*)xw + byteoff) = f2bf(av[o]);
            }
        }
    }
    __syncthreads();

    // ---- phase 2: wave = e; GEMM 16r x 128m, K=128 ----
    const int e  = t >> 6;
    const int l  = t & 63;
    const int lr = l & 15;    // A row r / B col m-offset
    const int lg = l >> 4;    // k-group

    bf16x8 afrag[4];
    #pragma unroll
    for (int ks = 0; ks < 4; ++ks) {
        int n0 = ks * 32 + lg * 8;
        int byteoff = (((e * 16 + lr) << 8) + (n0 << 1)) ^ ((lr & 7) << 4);
        short8 v = *(const short8*)((const char*)xw + byteoff);
        afrag[ks] = __builtin_bit_cast(bf16x8, v);
    }

    floatx4 acc[8];
    #pragma unroll
    for (int mt = 0; mt < 8; ++mt) acc[mt] = (floatx4){0.f, 0.f, 0.f, 0.f};

    const unsigned short* Ate = At + (size_t)e * 16384;
    #pragma unroll
    for (int mt = 0; mt < 8; ++mt) {
        int m = mt * 16 + lr;
        bf16x8 bfrag[4];
        #pragma unroll
        for (int ks = 0; ks < 4; ++ks) {
            int n0 = ks * 32 + lg * 8;
            short8 v = *(const short8*)(Ate + m * 128 + n0);
            bfrag[ks] = __builtin_bit_cast(bf16x8, v);
        }
        #pragma unroll
        for (int ks = 0; ks < 4; ++ks)
            acc[mt] = __builtin_amdgcn_mfma_f32_16x16x32_bf16(
                afrag[ks], bfrag[ks], acc[mt], 0, 0, 0);
    }

    // ---- epilogue: D col = lane&15 = m-offset; row = lg*4 + reg = bc_l*4 + o
    const int bc = bc0 + lg, b = bc >> 4, c = bc & 15;
    float4* outp = (float4*)out + ((size_t)(b * 64 + e * 16 + c) * 128);
    #pragma unroll
    for (int mt = 0; mt < 8; ++mt) {
        int m = mt * 16 + lr;
        float4 o4;
        o4.x = fmaxf(acc[mt][0], 0.f);
        o4.y = fmaxf(acc[mt][1], 0.f);
        o4.z = fmaxf(acc[mt][2], 0.f);
        o4.w = fmaxf(acc[mt][3], 0.f);
        outp[m] = o4;
    }
}

extern "C" void kernel_launch(void* const* d_in, const int* in_sizes, int n_in,
                              void* d_out, int out_size, void* d_ws, size_t ws_size,
                              hipStream_t stream) {
    const float* x = (const float*)d_in[0];   // [128,16,128,16]
    const float* A = (const float*)d_in[1];   // [4,128,128]
    const float* W = (const float*)d_in[2];   // [4,16,4]
    float* out = (float*)d_out;               // [128,64,128,4]
    unsigned short* At = (unsigned short*)d_ws;  // 4*128*128 bf16 = 128 KB

    prep_kernel<<<16, 256, 0, stream>>>(A, At);
    gcn_mfma_kernel<<<512, 256, 0, stream>>>(x, W, At, out);
}